// Round 4
// baseline (479.347 us; speedup 1.0000x reference)
//
#include <hip/hip_runtime.h>

#define NUM_NODES 262144
#define HIDDEN 256
#define NHID 128
#define NUM_GRAPHS 1024

typedef float f32x4 __attribute__((ext_vector_type(4)));
typedef short s16x8 __attribute__((ext_vector_type(8)));

// f32 -> bf16 bits with round-to-nearest-even
__device__ __forceinline__ short f2bf(float f) {
    unsigned u = __builtin_bit_cast(unsigned, f);
    unsigned r = (u + 0x7FFFu + ((u >> 16) & 1u)) >> 16;
    return (short)r;
}

// bf16 bits -> f32 (exact)
__device__ __forceinline__ float bf2f(short h) {
    return __builtin_bit_cast(float, ((unsigned)(unsigned short)h) << 16);
}

// tanh via native exp: ~6 VALU ops. Saturates correctly for large |v|.
__device__ __forceinline__ float fast_tanh(float v) {
    float e = __expf(2.0f * v);
    return 1.0f - __fdividef(2.0f, e + 1.0f);
}

// ---------------------------------------------------------------------------
// Kernel 0: swizzle W1 into bf16 MFMA fragment order + zero out/sums.
// ---------------------------------------------------------------------------
__global__ __launch_bounds__(256) void prep_w1(const float* __restrict__ W1,
                                               short* __restrict__ w1swz,
                                               float* __restrict__ out,
                                               float* __restrict__ sums) {
    int e = blockIdx.x * 256 + threadIdx.x;   // 0..4095
    f32x4 z = (f32x4){0.f, 0.f, 0.f, 0.f};
#pragma unroll
    for (int i = 0; i < 16; ++i)
        ((f32x4*)out)[e + i * 4096] = z;
    if (e < 256) ((f32x4*)sums)[e] = z;

    int l  = e & 63;
    int nt = (e >> 6) & 7;
    int kt = e >> 9;
    int kbase = kt * 32 + ((l >> 4) << 3);
    int n = nt * 16 + (l & 15);
#pragma unroll
    for (int j = 0; j < 8; ++j)
        w1swz[e * 8 + j] = f2bf(W1[(size_t)(kbase + j) * NHID + n]);
}

// ---------------------------------------------------------------------------
// Fused kernel, single-raw-buffer pipeline:
//   tile body = { issue tile g+1 loads into a[16] }  (in flight all body)
//               { MFMA + score + POOL, all reading af (tile g, bf16) }
//               { wait loads; convert a -> af }
// Pooling unpacks af (bf16 x) exactly; frees a[] at conversion so only ONE
// 64-VGPR raw buffer exists (R3's spill came from two).
// ---------------------------------------------------------------------------
#define FLUSH(G) do {                                                         \
    _Pragma("unroll")                                                         \
    for (int m_ = 1; m_ <= 8; m_ <<= 1) {                                     \
        _Pragma("unroll")                                                     \
        for (int i_ = 0; i_ < 16; ++i_) {                                     \
            accp[i_].x += __shfl_xor(accp[i_].x, m_);                         \
            accp[i_].y += __shfl_xor(accp[i_].y, m_);                         \
            accp[i_].z += __shfl_xor(accp[i_].z, m_);                         \
            accp[i_].w += __shfl_xor(accp[i_].w, m_);                         \
        }                                                                     \
        sum_e += __shfl_xor(sum_e, m_);                                       \
    }                                                                         \
    if (l15 == 0) {                                                           \
        float* vrow_ = out + (size_t)(G) * HIDDEN;                            \
        _Pragma("unroll")                                                     \
        for (int i_ = 0; i_ < 16; ++i_) {                                     \
            int colb_ = (i_ >> 1) * 32 + quad * 8 + (i_ & 1) * 4;             \
            atomicAdd(vrow_ + colb_ + 0, accp[i_].x);                         \
            atomicAdd(vrow_ + colb_ + 1, accp[i_].y);                         \
            atomicAdd(vrow_ + colb_ + 2, accp[i_].z);                         \
            atomicAdd(vrow_ + colb_ + 3, accp[i_].w);                         \
        }                                                                     \
        if (quad == 0) atomicAdd(&sums[G], sum_e);                            \
    }                                                                         \
    _Pragma("unroll")                                                         \
    for (int i_ = 0; i_ < 16; ++i_) accp[i_] = (f32x4){0.f, 0.f, 0.f, 0.f};   \
    sum_e = 0.f;                                                              \
} while (0)

// accp[2kt]   += x[kt*32+quad*8+0..3] * EW ; accp[2kt+1] += ...+4..7 * EW
// (af[kt][j] = bf16 of exactly those elements; bf2f unpack is exact)
#define POOL(EW) do {                                                         \
    _Pragma("unroll")                                                         \
    for (int kt_ = 0; kt_ < 8; ++kt_) {                                       \
        accp[2 * kt_].x     += bf2f(af[kt_][0]) * (EW);                       \
        accp[2 * kt_].y     += bf2f(af[kt_][1]) * (EW);                       \
        accp[2 * kt_].z     += bf2f(af[kt_][2]) * (EW);                       \
        accp[2 * kt_].w     += bf2f(af[kt_][3]) * (EW);                       \
        accp[2 * kt_ + 1].x += bf2f(af[kt_][4]) * (EW);                       \
        accp[2 * kt_ + 1].y += bf2f(af[kt_][5]) * (EW);                       \
        accp[2 * kt_ + 1].z += bf2f(af[kt_][6]) * (EW);                       \
        accp[2 * kt_ + 1].w += bf2f(af[kt_][7]) * (EW);                       \
    }                                                                         \
    sum_e += (EW);                                                            \
} while (0)

__global__ __launch_bounds__(256, 2) void fused_kernel(
    const float* __restrict__ x, const int* __restrict__ batch,
    const short* __restrict__ w1swz, const float* __restrict__ b1,
    const float* __restrict__ W2, const float* __restrict__ b2,
    float* __restrict__ out, float* __restrict__ sums) {
    __shared__ short w1s[32768];   // 64 KB fragment-ordered bf16 W1
    __shared__ float bw[256];      // [nt][quad][j]: j<4 -> b1, j>=4 -> W2

    int tid = threadIdx.x;
    for (int i = tid; i < 4096; i += 256)
        ((f32x4*)w1s)[i] = ((const f32x4*)w1swz)[i];
    {
        int nt = tid >> 5, q = (tid >> 3) & 3, j = tid & 7;
        bw[tid] = (j < 4) ? b1[nt * 16 + q * 4 + j]
                          : W2[nt * 16 + q * 4 + (j - 4)];
    }
    __syncthreads();

    int wave = tid >> 6, lane = tid & 63;
    int quad = lane >> 4, l15 = lane & 15;
    float b2v = b2[0];

    f32x4 accp[16];
#pragma unroll
    for (int i = 0; i < 16; ++i) accp[i] = (f32x4){0.f, 0.f, 0.f, 0.f};
    float sum_e = 0.f;
    int base = blockIdx.x * 512 + wave * 128;   // wave owns 128 contiguous nodes
    int cur_g = batch[base];

    f32x4 a[16];       // in-flight raw tile (the only 64-VGPR buffer)
    s16x8 af[8];       // current tile, bf16 fragments (MFMA + pooling source)
    int bgC, bgN;

    // Prologue: load + convert tile 0
    {
        const float* xr = x + (size_t)(base + l15) * HIDDEN + quad * 8;
#pragma unroll
        for (int kt = 0; kt < 8; ++kt) {
            a[2 * kt]     = *(const f32x4*)(xr + kt * 32);
            a[2 * kt + 1] = *(const f32x4*)(xr + kt * 32 + 4);
        }
        bgC = batch[base + l15];
#pragma unroll
        for (int kt = 0; kt < 8; ++kt) {
            f32x4 a0 = a[2 * kt], a1 = a[2 * kt + 1];
            af[kt][0] = f2bf(a0.x); af[kt][1] = f2bf(a0.y);
            af[kt][2] = f2bf(a0.z); af[kt][3] = f2bf(a0.w);
            af[kt][4] = f2bf(a1.x); af[kt][5] = f2bf(a1.y);
            af[kt][6] = f2bf(a1.z); af[kt][7] = f2bf(a1.w);
        }
    }

    for (int g = 0; g < 8; ++g) {
        // 1) issue next tile's loads — in flight through the whole body
        if (g < 7) {
            const float* xr = x + (size_t)(base + (g + 1) * 16 + l15) * HIDDEN + quad * 8;
#pragma unroll
            for (int kt = 0; kt < 8; ++kt) {
                a[2 * kt]     = *(const f32x4*)(xr + kt * 32);
                a[2 * kt + 1] = *(const f32x4*)(xr + kt * 32 + 4);
            }
            bgN = batch[base + (g + 1) * 16 + l15];
        }
        int my_g = bgC;

        // 2) Ht = W1^T @ X^T from af (swapped-operand MFMA)
        f32x4 acc[8];
#pragma unroll
        for (int nt = 0; nt < 8; ++nt) acc[nt] = (f32x4){0.f, 0.f, 0.f, 0.f};
#pragma unroll
        for (int kt = 0; kt < 8; ++kt) {
#pragma unroll
            for (int nt = 0; nt < 8; ++nt) {
                s16x8 bf = *(const s16x8*)&w1s[((kt * 8 + nt) * 64 + lane) * 8];
                acc[nt] = __builtin_amdgcn_mfma_f32_16x16x32_bf16(bf, af[kt], acc[nt], 0, 0, 0);
            }
        }

        // 3) score -> every lane holds s for its own node l15
        float p = 0.f;
#pragma unroll
        for (int nt = 0; nt < 8; ++nt) {
            f32x4 b1q = *(f32x4*)&bw[nt * 32 + quad * 8];
            f32x4 w2q = *(f32x4*)&bw[nt * 32 + quad * 8 + 4];
#pragma unroll
            for (int r = 0; r < 4; ++r)
                p += fast_tanh(acc[nt][r] + b1q[r]) * w2q[r];
        }
        p += __shfl_xor(p, 16);
        p += __shfl_xor(p, 32);
        float e = __expf(p + b2v);

        // 4) segmented pooling from af (batch sorted; boundaries rare)
        int first_g = __shfl(my_g, 0);
        int last_g  = __shfl(my_g, 15);
        if (first_g != cur_g) { FLUSH(cur_g); cur_g = first_g; }
        if (last_g == cur_g) {
            POOL(e);
        } else {
            int g_seg = cur_g;
            while (true) {
                float em = (my_g == g_seg) ? e : 0.f;
                POOL(em);
                FLUSH(g_seg);
                unsigned long long bal = __ballot(my_g > g_seg);
                if (!bal) break;
                g_seg = __shfl(my_g, __ffsll(bal) - 1);
            }
            cur_g = last_g;
        }

        // 5) landed loads -> bf16 fragments for next iteration
        if (g < 7) {
#pragma unroll
            for (int kt = 0; kt < 8; ++kt) {
                f32x4 a0 = a[2 * kt], a1 = a[2 * kt + 1];
                af[kt][0] = f2bf(a0.x); af[kt][1] = f2bf(a0.y);
                af[kt][2] = f2bf(a0.z); af[kt][3] = f2bf(a0.w);
                af[kt][4] = f2bf(a1.x); af[kt][5] = f2bf(a1.y);
                af[kt][6] = f2bf(a1.z); af[kt][7] = f2bf(a1.w);
            }
            bgC = bgN;
        }
    }
    FLUSH(cur_g);
}

// ---------------------------------------------------------------------------
// Finalize in place: out[g][c] /= (sums[g] + 1e-8)
// ---------------------------------------------------------------------------
__global__ __launch_bounds__(256) void norm_kernel(
    float* __restrict__ out, const float* __restrict__ sums) {
    int idx = blockIdx.x * 256 + threadIdx.x;
    float inv = 1.0f / (sums[idx >> 8] + 1e-8f);
    out[idx] = out[idx] * inv;
}

extern "C" void kernel_launch(void* const* d_in, const int* in_sizes, int n_in,
                              void* d_out, int out_size, void* d_ws, size_t ws_size,
                              hipStream_t stream) {
    const float* x     = (const float*)d_in[0];
    const int*   batch = (const int*)d_in[1];
    const float* W1    = (const float*)d_in[2];
    const float* b1    = (const float*)d_in[3];
    const float* W2    = (const float*)d_in[4];
    const float* b2    = (const float*)d_in[5];
    float* out = (float*)d_out;

    char* ws = (char*)d_ws;
    float* sums  = (float*)ws;                          // 4 KB
    short* w1swz = (short*)(ws + NUM_GRAPHS * 4);       // 64 KB

    hipLaunchKernelGGL(prep_w1, dim3(16), dim3(256), 0, stream,
                       W1, w1swz, out, sums);
    hipLaunchKernelGGL(fused_kernel, dim3(512), dim3(256), 0, stream,
                       x, batch, w1swz, b1, W2, b2, out, sums);
    hipLaunchKernelGGL(norm_kernel, dim3(NUM_GRAPHS * HIDDEN / 256), dim3(256), 0, stream,
                       out, sums);
}

// Round 5
// 392.614 us; speedup vs baseline: 1.2209x; 1.2209x over previous
//
#include <hip/hip_runtime.h>

#define NUM_NODES 262144
#define HIDDEN 256
#define NHID 128
#define NUM_GRAPHS 1024

typedef float f32x4 __attribute__((ext_vector_type(4)));
typedef short s16x8 __attribute__((ext_vector_type(8)));

// f32 -> bf16 bits with round-to-nearest-even
__device__ __forceinline__ short f2bf(float f) {
    unsigned u = __builtin_bit_cast(unsigned, f);
    unsigned r = (u + 0x7FFFu + ((u >> 16) & 1u)) >> 16;
    return (short)r;
}

// bf16 bits -> f32 (exact)
__device__ __forceinline__ float bf2f(short h) {
    return __builtin_bit_cast(float, ((unsigned)(unsigned short)h) << 16);
}

// tanh via native exp: ~6 VALU ops. Saturates correctly for large |v|.
__device__ __forceinline__ float fast_tanh(float v) {
    float e = __expf(2.0f * v);
    return 1.0f - __fdividef(2.0f, e + 1.0f);
}

// ---------------------------------------------------------------------------
// Kernel 0: swizzle W1 into bf16 MFMA fragment order + zero out/sums.
// ---------------------------------------------------------------------------
__global__ __launch_bounds__(256) void prep_w1(const float* __restrict__ W1,
                                               short* __restrict__ w1swz,
                                               float* __restrict__ out,
                                               float* __restrict__ sums) {
    int e = blockIdx.x * 256 + threadIdx.x;   // 0..4095
    f32x4 z = (f32x4){0.f, 0.f, 0.f, 0.f};
#pragma unroll
    for (int i = 0; i < 16; ++i)
        ((f32x4*)out)[e + i * 4096] = z;
    if (e < 256) ((f32x4*)sums)[e] = z;

    int l  = e & 63;
    int nt = (e >> 6) & 7;
    int kt = e >> 9;
    int kbase = kt * 32 + ((l >> 4) << 3);
    int n = nt * 16 + (l & 15);
#pragma unroll
    for (int j = 0; j < 8; ++j)
        w1swz[e * 8 + j] = f2bf(W1[(size_t)(kbase + j) * NHID + n]);
}

// ---------------------------------------------------------------------------
// Fused kernel, pipelined with STRAIGHT-LINE segmented pooling.
// R3/R4 spilled because a[16] (in-flight loads) stayed live across a
// data-dependent while/ballot loop -> allocator clamped to 128 VGPR + spill.
// Graphs are 256±16 nodes, so a 16-row tile spans <=2 graphs: the segmented
// pool is two masked POOLs + one FLUSH, no loop. launch_bounds(256,1)
// relaxes the occupancy target so ~215 live VGPRs fit without spilling.
// ---------------------------------------------------------------------------
#define FLUSH(G) do {                                                         \
    _Pragma("unroll")                                                         \
    for (int m_ = 1; m_ <= 8; m_ <<= 1) {                                     \
        _Pragma("unroll")                                                     \
        for (int i_ = 0; i_ < 16; ++i_) {                                     \
            accp[i_].x += __shfl_xor(accp[i_].x, m_);                         \
            accp[i_].y += __shfl_xor(accp[i_].y, m_);                         \
            accp[i_].z += __shfl_xor(accp[i_].z, m_);                         \
            accp[i_].w += __shfl_xor(accp[i_].w, m_);                         \
        }                                                                     \
        sum_e += __shfl_xor(sum_e, m_);                                       \
    }                                                                         \
    if (l15 == 0) {                                                           \
        float* vrow_ = out + (size_t)(G) * HIDDEN;                            \
        _Pragma("unroll")                                                     \
        for (int i_ = 0; i_ < 16; ++i_) {                                     \
            int colb_ = (i_ >> 1) * 32 + quad * 8 + (i_ & 1) * 4;             \
            atomicAdd(vrow_ + colb_ + 0, accp[i_].x);                         \
            atomicAdd(vrow_ + colb_ + 1, accp[i_].y);                         \
            atomicAdd(vrow_ + colb_ + 2, accp[i_].z);                         \
            atomicAdd(vrow_ + colb_ + 3, accp[i_].w);                         \
        }                                                                     \
        if (quad == 0) atomicAdd(&sums[G], sum_e);                            \
    }                                                                         \
    _Pragma("unroll")                                                         \
    for (int i_ = 0; i_ < 16; ++i_) accp[i_] = (f32x4){0.f, 0.f, 0.f, 0.f};   \
    sum_e = 0.f;                                                              \
} while (0)

// accp += (bf16 x, exact unpack) * EW ; sum_e += EW
#define POOL(EW) do {                                                         \
    _Pragma("unroll")                                                         \
    for (int kt_ = 0; kt_ < 8; ++kt_) {                                       \
        accp[2 * kt_].x     += bf2f(af[kt_][0]) * (EW);                       \
        accp[2 * kt_].y     += bf2f(af[kt_][1]) * (EW);                       \
        accp[2 * kt_].z     += bf2f(af[kt_][2]) * (EW);                       \
        accp[2 * kt_].w     += bf2f(af[kt_][3]) * (EW);                       \
        accp[2 * kt_ + 1].x += bf2f(af[kt_][4]) * (EW);                       \
        accp[2 * kt_ + 1].y += bf2f(af[kt_][5]) * (EW);                       \
        accp[2 * kt_ + 1].z += bf2f(af[kt_][6]) * (EW);                       \
        accp[2 * kt_ + 1].w += bf2f(af[kt_][7]) * (EW);                       \
    }                                                                         \
    sum_e += (EW);                                                            \
} while (0)

__global__ __launch_bounds__(256, 1) void fused_kernel(
    const float* __restrict__ x, const int* __restrict__ batch,
    const short* __restrict__ w1swz, const float* __restrict__ b1,
    const float* __restrict__ W2, const float* __restrict__ b2,
    float* __restrict__ out, float* __restrict__ sums) {
    __shared__ short w1s[32768];   // 64 KB fragment-ordered bf16 W1
    __shared__ float bw[256];      // [nt][quad][j]: j<4 -> b1, j>=4 -> W2

    int tid = threadIdx.x;
    for (int i = tid; i < 4096; i += 256)
        ((f32x4*)w1s)[i] = ((const f32x4*)w1swz)[i];
    {
        int nt = tid >> 5, q = (tid >> 3) & 3, j = tid & 7;
        bw[tid] = (j < 4) ? b1[nt * 16 + q * 4 + j]
                          : W2[nt * 16 + q * 4 + (j - 4)];
    }
    __syncthreads();

    int wave = tid >> 6, lane = tid & 63;
    int quad = lane >> 4, l15 = lane & 15;
    float b2v = b2[0];

    f32x4 accp[16];
#pragma unroll
    for (int i = 0; i < 16; ++i) accp[i] = (f32x4){0.f, 0.f, 0.f, 0.f};
    float sum_e = 0.f;
    int base = blockIdx.x * 512 + wave * 128;   // wave owns 128 contiguous nodes
    int cur_g = batch[base];

    f32x4 a[16];       // in-flight raw tile
    s16x8 af[8];       // current tile, bf16 fragments (MFMA + pooling source)
    int bgC, bgN;

    // Prologue: load + convert tile 0
    {
        const float* xr = x + (size_t)(base + l15) * HIDDEN + quad * 8;
#pragma unroll
        for (int kt = 0; kt < 8; ++kt) {
            a[2 * kt]     = *(const f32x4*)(xr + kt * 32);
            a[2 * kt + 1] = *(const f32x4*)(xr + kt * 32 + 4);
        }
        bgC = batch[base + l15];
#pragma unroll
        for (int kt = 0; kt < 8; ++kt) {
            f32x4 a0 = a[2 * kt], a1 = a[2 * kt + 1];
            af[kt][0] = f2bf(a0.x); af[kt][1] = f2bf(a0.y);
            af[kt][2] = f2bf(a0.z); af[kt][3] = f2bf(a0.w);
            af[kt][4] = f2bf(a1.x); af[kt][5] = f2bf(a1.y);
            af[kt][6] = f2bf(a1.z); af[kt][7] = f2bf(a1.w);
        }
    }

    for (int g = 0; g < 8; ++g) {
        // 1) issue next tile's loads — in flight through the whole body
        if (g < 7) {
            const float* xr = x + (size_t)(base + (g + 1) * 16 + l15) * HIDDEN + quad * 8;
#pragma unroll
            for (int kt = 0; kt < 8; ++kt) {
                a[2 * kt]     = *(const f32x4*)(xr + kt * 32);
                a[2 * kt + 1] = *(const f32x4*)(xr + kt * 32 + 4);
            }
            bgN = batch[base + (g + 1) * 16 + l15];
        }
        int my_g = bgC;

        // 2) Ht = W1^T @ X^T from af (swapped-operand MFMA)
        f32x4 acc[8];
#pragma unroll
        for (int nt = 0; nt < 8; ++nt) acc[nt] = (f32x4){0.f, 0.f, 0.f, 0.f};
#pragma unroll
        for (int kt = 0; kt < 8; ++kt) {
#pragma unroll
            for (int nt = 0; nt < 8; ++nt) {
                s16x8 bf = *(const s16x8*)&w1s[((kt * 8 + nt) * 64 + lane) * 8];
                acc[nt] = __builtin_amdgcn_mfma_f32_16x16x32_bf16(bf, af[kt], acc[nt], 0, 0, 0);
            }
        }

        // 3) score -> every lane holds s for its own node l15
        float p = 0.f;
#pragma unroll
        for (int nt = 0; nt < 8; ++nt) {
            f32x4 b1q = *(f32x4*)&bw[nt * 32 + quad * 8];
            f32x4 w2q = *(f32x4*)&bw[nt * 32 + quad * 8 + 4];
#pragma unroll
            for (int r = 0; r < 4; ++r)
                p += fast_tanh(acc[nt][r] + b1q[r]) * w2q[r];
        }
        p += __shfl_xor(p, 16);
        p += __shfl_xor(p, 32);
        float e = __expf(p + b2v);

        // 4) segmented pooling, STRAIGHT-LINE (tile spans <=2 graphs:
        //    graph sizes are 256±16 >> 16, so no loop needed)
        int first_g = __shfl(my_g, 0);
        int last_g  = __shfl(my_g, 15);
        if (first_g != cur_g) { FLUSH(cur_g); cur_g = first_g; }
        if (last_g == cur_g) {
            POOL(e);
        } else {
            float e0 = (my_g == cur_g) ? e : 0.f;
            POOL(e0);
            FLUSH(cur_g);
            float e1 = (my_g == last_g) ? e : 0.f;
            POOL(e1);
            cur_g = last_g;
        }

        // 5) landed loads -> bf16 fragments for next iteration
        if (g < 7) {
#pragma unroll
            for (int kt = 0; kt < 8; ++kt) {
                f32x4 a0 = a[2 * kt], a1 = a[2 * kt + 1];
                af[kt][0] = f2bf(a0.x); af[kt][1] = f2bf(a0.y);
                af[kt][2] = f2bf(a0.z); af[kt][3] = f2bf(a0.w);
                af[kt][4] = f2bf(a1.x); af[kt][5] = f2bf(a1.y);
                af[kt][6] = f2bf(a1.z); af[kt][7] = f2bf(a1.w);
            }
            bgC = bgN;
        }
    }
    FLUSH(cur_g);
}

// ---------------------------------------------------------------------------
// Finalize in place: out[g][c] /= (sums[g] + 1e-8)
// ---------------------------------------------------------------------------
__global__ __launch_bounds__(256) void norm_kernel(
    float* __restrict__ out, const float* __restrict__ sums) {
    int idx = blockIdx.x * 256 + threadIdx.x;
    float inv = 1.0f / (sums[idx >> 8] + 1e-8f);
    out[idx] = out[idx] * inv;
}

extern "C" void kernel_launch(void* const* d_in, const int* in_sizes, int n_in,
                              void* d_out, int out_size, void* d_ws, size_t ws_size,
                              hipStream_t stream) {
    const float* x     = (const float*)d_in[0];
    const int*   batch = (const int*)d_in[1];
    const float* W1    = (const float*)d_in[2];
    const float* b1    = (const float*)d_in[3];
    const float* W2    = (const float*)d_in[4];
    const float* b2    = (const float*)d_in[5];
    float* out = (float*)d_out;

    char* ws = (char*)d_ws;
    float* sums  = (float*)ws;                          // 4 KB
    short* w1swz = (short*)(ws + NUM_GRAPHS * 4);       // 64 KB

    hipLaunchKernelGGL(prep_w1, dim3(16), dim3(256), 0, stream,
                       W1, w1swz, out, sums);
    hipLaunchKernelGGL(fused_kernel, dim3(512), dim3(256), 0, stream,
                       x, batch, w1swz, b1, W2, b2, out, sums);
    hipLaunchKernelGGL(norm_kernel, dim3(NUM_GRAPHS * HIDDEN / 256), dim3(256), 0, stream,
                       out, sums);
}